// Round 1
// baseline (855.859 us; speedup 1.0000x reference)
//
#include <hip/hip_runtime.h>

typedef __attribute__((ext_vector_type(8))) short short8;
typedef __attribute__((ext_vector_type(8))) unsigned short ushort8;
typedef __attribute__((ext_vector_type(4))) float floatx4;

#define T_TOK 1024
#define H_DIM 2048
#define I_DIM 768
#define E_NUM 32
#define TOPK  8

// ---- workspace layout (bytes) ----
#define OFF_CNT   0                      // 32 * 4
#define OFF_OFFS  512                    // 33 * 4
#define OFF_LIST  1024                   // 32*1024*4 = 131072
#define OFF_TIDX  (OFF_LIST + 131072)    // 1024*8*4
#define OFF_TPOS  (OFF_TIDX + 32768)     // 1024*8*4
#define OFF_TW    (OFF_TPOS + 32768)     // 1024*8*4
#define OFF_GU    262144                 // 8192*1536*2 = 25165824 (bf16)
#define OFF_Y     (OFF_GU + 25165824)    // 8192*2048*2 = 33554432 (bf16)

__device__ __forceinline__ unsigned short f2bf(float f) {
  unsigned int u = __builtin_bit_cast(unsigned int, f);
  u += 0x7fffu + ((u >> 16) & 1u);           // RNE
  return (unsigned short)(u >> 16);
}
__device__ __forceinline__ float bf2f(unsigned short h) {
  unsigned int u = ((unsigned int)h) << 16;
  return __builtin_bit_cast(float, u);
}

// ---------------- router: logits (fp32, exact) + softmax + top8 + assignment ----------------
__global__ __launch_bounds__(256) void router_kernel(
    const float* __restrict__ x, const float* __restrict__ gw,
    float* __restrict__ logits_out, int* __restrict__ cnt, int* __restrict__ list,
    int* __restrict__ tidx, int* __restrict__ tpos, float* __restrict__ tw)
{
  int t = blockIdx.x;
  int tid = threadIdx.x;
  int wave = tid >> 6, lane = tid & 63;
  const float* xr = x + (size_t)t * H_DIM;
  float xv[32];
#pragma unroll
  for (int i = 0; i < 32; i++) xv[i] = xr[lane + 64 * i];

  __shared__ float lg[E_NUM];
  for (int ee = 0; ee < 8; ee++) {
    int e = wave * 8 + ee;
    const float* wr = gw + (size_t)e * H_DIM;
    float acc = 0.f;
#pragma unroll
    for (int i = 0; i < 32; i++) acc += xv[i] * wr[lane + 64 * i];
    for (int m = 32; m >= 1; m >>= 1) acc += __shfl_xor(acc, m, 64);
    if (lane == 0) lg[e] = acc;
  }
  __syncthreads();

  if (tid < E_NUM) logits_out[t * E_NUM + tid] = lg[tid];

  if (wave == 0) {
    float logit = (lane < E_NUM) ? lg[lane] : -1e30f;
    float mx = logit;
    for (int m = 16; m >= 1; m >>= 1) mx = fmaxf(mx, __shfl_xor(mx, m, 64));
    float p = (lane < E_NUM) ? expf(logit - mx) : 0.f;
    float sum = p;
    for (int m = 16; m >= 1; m >>= 1) sum += __shfl_xor(sum, m, 64);
    p /= sum;

    float rem = (lane < E_NUM) ? p : -1.f;
    int   seli[TOPK];
    float selw[TOPK];
    float sumw = 0.f;
#pragma unroll
    for (int k = 0; k < TOPK; k++) {
      float v = rem; int i = lane;
      for (int m = 16; m >= 1; m >>= 1) {
        float ov = __shfl_xor(v, m, 64);
        int   oi = __shfl_xor(i, m, 64);
        if (ov > v || (ov == v && oi < i)) { v = ov; i = oi; }
      }
      seli[k] = i; selw[k] = v; sumw += v;
      if (lane == i) rem = -1.f;
    }
    if (lane < TOPK) {
      int e = seli[lane];
      float w = selw[lane] / sumw;
      int pos = atomicAdd(&cnt[e], 1);
      list[e * 1024 + pos] = t;
      tidx[t * TOPK + lane] = e;
      tpos[t * TOPK + lane] = pos;
      tw[t * TOPK + lane] = w;
    }
  }
}

// ---------------- exclusive scan of expert counts ----------------
__global__ void scan_kernel(const int* __restrict__ cnt, int* __restrict__ offs) {
  if (threadIdx.x == 0) {
    int s = 0;
    for (int e = 0; e < E_NUM; e++) { offs[e] = s; s += cnt[e]; }
    offs[E_NUM] = s;
  }
}

// ---------------- grouped GEMM: gate/up (bf16 MFMA), C = X * W^T ----------------
__global__ __launch_bounds__(256) void gemm_gu(
    const float* __restrict__ x,
    const float* __restrict__ gpw, const float* __restrict__ upw,
    const int* __restrict__ cnt, const int* __restrict__ offs,
    const int* __restrict__ list, unsigned short* __restrict__ gu)
{
  int e = blockIdx.y;
  int c = cnt[e];
  if (c == 0) return;
  int nt = blockIdx.x;                 // 0..11 : 6 gate tiles then 6 up tiles
  int isup = (nt >= 6) ? 1 : 0;
  int n0 = (nt - 6 * isup) * 128;
  const float* W = (isup ? upw : gpw) + ((size_t)e * I_DIM + n0) * H_DIM;
  int guoff = isup * I_DIM;
  int base = offs[e];

  __shared__ unsigned short Xs[128 * 40];
  __shared__ unsigned short Ws[128 * 40];

  int tid = threadIdx.x;
  int wave = tid >> 6, lane = tid & 63;
  int mq = wave >> 1, nq = wave & 1;
  int q = lane >> 4, l15 = lane & 15;

  int r0 = tid >> 2, c8 = tid & 3;
  int r1 = r0 + 64;
  const float* Wp0 = W + (size_t)r0 * H_DIM + c8 * 8;
  const float* Wp1 = W + (size_t)r1 * H_DIM + c8 * 8;

  int mtiles = (c + 127) >> 7;
  for (int mt = 0; mt < mtiles; mt++) {
    int s0 = mt * 128 + r0, s1 = mt * 128 + r1;
    int t0 = list[e * 1024 + (s0 < c ? s0 : c - 1)];
    int t1 = list[e * 1024 + (s1 < c ? s1 : c - 1)];
    const float* Xp0 = x + (size_t)t0 * H_DIM + c8 * 8;
    const float* Xp1 = x + (size_t)t1 * H_DIM + c8 * 8;

    floatx4 acc[4][4];
#pragma unroll
    for (int i = 0; i < 4; i++)
#pragma unroll
      for (int j = 0; j < 4; j++) acc[i][j] = (floatx4){0.f, 0.f, 0.f, 0.f};

    for (int kt = 0; kt < 64; kt++) {
      int k0 = kt * 32;
      floatx4 a0 = *(const floatx4*)(Xp0 + k0);
      floatx4 a1 = *(const floatx4*)(Xp0 + k0 + 4);
      floatx4 b0 = *(const floatx4*)(Xp1 + k0);
      floatx4 b1 = *(const floatx4*)(Xp1 + k0 + 4);
      floatx4 w0 = *(const floatx4*)(Wp0 + k0);
      floatx4 w1 = *(const floatx4*)(Wp0 + k0 + 4);
      floatx4 v0 = *(const floatx4*)(Wp1 + k0);
      floatx4 v1 = *(const floatx4*)(Wp1 + k0 + 4);
      ushort8 px, py, pw, pv;
#pragma unroll
      for (int i = 0; i < 4; i++) {
        px[i] = f2bf(a0[i]); px[i + 4] = f2bf(a1[i]);
        py[i] = f2bf(b0[i]); py[i + 4] = f2bf(b1[i]);
        pw[i] = f2bf(w0[i]); pw[i + 4] = f2bf(w1[i]);
        pv[i] = f2bf(v0[i]); pv[i + 4] = f2bf(v1[i]);
      }
      *(ushort8*)&Xs[r0 * 40 + c8 * 8] = px;
      *(ushort8*)&Xs[r1 * 40 + c8 * 8] = py;
      *(ushort8*)&Ws[r0 * 40 + c8 * 8] = pw;
      *(ushort8*)&Ws[r1 * 40 + c8 * 8] = pv;
      __syncthreads();

      short8 af[4], bf_[4];
#pragma unroll
      for (int i = 0; i < 4; i++) af[i] = *(const short8*)&Xs[(mq * 64 + i * 16 + l15) * 40 + q * 8];
#pragma unroll
      for (int j = 0; j < 4; j++) bf_[j] = *(const short8*)&Ws[(nq * 64 + j * 16 + l15) * 40 + q * 8];
#pragma unroll
      for (int i = 0; i < 4; i++)
#pragma unroll
        for (int j = 0; j < 4; j++)
          acc[i][j] = __builtin_amdgcn_mfma_f32_16x16x32_bf16(af[i], bf_[j], acc[i][j], 0, 0, 0);
      __syncthreads();
    }

#pragma unroll
    for (int i = 0; i < 4; i++) {
#pragma unroll
      for (int r = 0; r < 4; r++) {
        int m = mq * 64 + i * 16 + q * 4 + r;
        int s = mt * 128 + m;
        if (s < c) {
          size_t rowbase = (size_t)(base + s) * 1536 + guoff;
#pragma unroll
          for (int j = 0; j < 4; j++) {
            int n = n0 + nq * 64 + j * 16 + l15;
            gu[rowbase + n] = f2bf(acc[i][j][r]);
          }
        }
      }
    }
  }
}

// ---------------- act = silu(g) * u, in place over gate half ----------------
__global__ __launch_bounds__(256) void silu_mul(unsigned short* __restrict__ gu) {
  unsigned int cid = blockIdx.x * 256 + threadIdx.x;   // 8192 slots * 96 chunks
  unsigned int slot = cid / 96;
  unsigned int ch = cid - slot * 96;
  size_t off = (size_t)slot * 1536 + ch * 8;
  ushort8 g8 = *(ushort8*)(gu + off);
  ushort8 u8 = *(ushort8*)(gu + off + 768);
  ushort8 o;
#pragma unroll
  for (int j = 0; j < 8; j++) {
    float g = bf2f(g8[j]);
    float u = bf2f(u8[j]);
    float s = g / (1.f + __expf(-g));
    o[j] = f2bf(s * u);
  }
  *(ushort8*)(gu + off) = o;
}

// ---------------- grouped GEMM: down proj, Y = act * Wd^T ----------------
__global__ __launch_bounds__(256) void gemm_down(
    const unsigned short* __restrict__ act,   // gu, row stride 1536, cols 0..767
    const float* __restrict__ dpw,
    const int* __restrict__ cnt, const int* __restrict__ offs,
    unsigned short* __restrict__ y)
{
  int e = blockIdx.y;
  int c = cnt[e];
  if (c == 0) return;
  int h0 = blockIdx.x * 128;                 // 16 tiles over H
  const float* W = dpw + ((size_t)e * H_DIM + h0) * I_DIM;
  int base = offs[e];

  __shared__ unsigned short Xs[128 * 40];
  __shared__ unsigned short Ws[128 * 40];

  int tid = threadIdx.x;
  int wave = tid >> 6, lane = tid & 63;
  int mq = wave >> 1, nq = wave & 1;
  int q = lane >> 4, l15 = lane & 15;

  int r0 = tid >> 2, c8 = tid & 3;
  int r1 = r0 + 64;
  const float* Wp0 = W + (size_t)r0 * I_DIM + c8 * 8;
  const float* Wp1 = W + (size_t)r1 * I_DIM + c8 * 8;

  int mtiles = (c + 127) >> 7;
  for (int mt = 0; mt < mtiles; mt++) {
    int s0 = mt * 128 + r0, s1 = mt * 128 + r1;
    size_t sg0 = base + (s0 < c ? s0 : c - 1);
    size_t sg1 = base + (s1 < c ? s1 : c - 1);
    const unsigned short* Ap0 = act + sg0 * 1536 + c8 * 8;
    const unsigned short* Ap1 = act + sg1 * 1536 + c8 * 8;

    floatx4 acc[4][4];
#pragma unroll
    for (int i = 0; i < 4; i++)
#pragma unroll
      for (int j = 0; j < 4; j++) acc[i][j] = (floatx4){0.f, 0.f, 0.f, 0.f};

    for (int kt = 0; kt < 24; kt++) {
      int k0 = kt * 32;
      ushort8 px = *(const ushort8*)(Ap0 + k0);
      ushort8 py = *(const ushort8*)(Ap1 + k0);
      floatx4 w0 = *(const floatx4*)(Wp0 + k0);
      floatx4 w1 = *(const floatx4*)(Wp0 + k0 + 4);
      floatx4 v0 = *(const floatx4*)(Wp1 + k0);
      floatx4 v1 = *(const floatx4*)(Wp1 + k0 + 4);
      ushort8 pw, pv;
#pragma unroll
      for (int i = 0; i < 4; i++) {
        pw[i] = f2bf(w0[i]); pw[i + 4] = f2bf(w1[i]);
        pv[i] = f2bf(v0[i]); pv[i + 4] = f2bf(v1[i]);
      }
      *(ushort8*)&Xs[r0 * 40 + c8 * 8] = px;
      *(ushort8*)&Xs[r1 * 40 + c8 * 8] = py;
      *(ushort8*)&Ws[r0 * 40 + c8 * 8] = pw;
      *(ushort8*)&Ws[r1 * 40 + c8 * 8] = pv;
      __syncthreads();

      short8 af[4], bf_[4];
#pragma unroll
      for (int i = 0; i < 4; i++) af[i] = *(const short8*)&Xs[(mq * 64 + i * 16 + l15) * 40 + q * 8];
#pragma unroll
      for (int j = 0; j < 4; j++) bf_[j] = *(const short8*)&Ws[(nq * 64 + j * 16 + l15) * 40 + q * 8];
#pragma unroll
      for (int i = 0; i < 4; i++)
#pragma unroll
        for (int j = 0; j < 4; j++)
          acc[i][j] = __builtin_amdgcn_mfma_f32_16x16x32_bf16(af[i], bf_[j], acc[i][j], 0, 0, 0);
      __syncthreads();
    }

#pragma unroll
    for (int i = 0; i < 4; i++) {
#pragma unroll
      for (int r = 0; r < 4; r++) {
        int m = mq * 64 + i * 16 + q * 4 + r;
        int s = mt * 128 + m;
        if (s < c) {
          size_t rowbase = (size_t)(base + s) * 2048 + h0;
#pragma unroll
          for (int j = 0; j < 4; j++) {
            int n = nq * 64 + j * 16 + l15;
            y[rowbase + n] = f2bf(acc[i][j][r]);
          }
        }
      }
    }
  }
}

// ---------------- combine: out[t,h] = sum_k w * y[slot_k, h] ----------------
__global__ __launch_bounds__(256) void combine_kernel(
    const unsigned short* __restrict__ y,
    const int* __restrict__ tidx, const int* __restrict__ tpos,
    const float* __restrict__ tw, const int* __restrict__ offs,
    float* __restrict__ out)
{
  int t = blockIdx.x;
  int tid = threadIdx.x;
  int h = tid * 8;
  float acc[8];
#pragma unroll
  for (int j = 0; j < 8; j++) acc[j] = 0.f;
#pragma unroll
  for (int k = 0; k < TOPK; k++) {
    int e = tidx[t * TOPK + k];
    int p = tpos[t * TOPK + k];
    float w = tw[t * TOPK + k];
    size_t sg = (size_t)offs[e] + p;
    ushort8 v = *(const ushort8*)(y + sg * 2048 + h);
#pragma unroll
    for (int j = 0; j < 8; j++) acc[j] += w * bf2f(v[j]);
  }
  floatx4 o0 = {acc[0], acc[1], acc[2], acc[3]};
  floatx4 o1 = {acc[4], acc[5], acc[6], acc[7]};
  *(floatx4*)(out + (size_t)t * 2048 + h) = o0;
  *(floatx4*)(out + (size_t)t * 2048 + h + 4) = o1;
}

extern "C" void kernel_launch(void* const* d_in, const int* in_sizes, int n_in,
                              void* d_out, int out_size, void* d_ws, size_t ws_size,
                              hipStream_t stream) {
  const float* x   = (const float*)d_in[0];   // [1,1024,2048]
  const float* gw  = (const float*)d_in[1];   // [32,2048]
  const float* gpw = (const float*)d_in[2];   // [32,768,2048]
  const float* upw = (const float*)d_in[3];   // [32,768,2048]
  const float* dpw = (const float*)d_in[4];   // [32,2048,768]
  float* out = (float*)d_out;                 // final (2097152) ++ router_logits (32768)
  float* logits_out = out + (size_t)T_TOK * H_DIM;

  char* ws = (char*)d_ws;
  int*   cnt  = (int*)(ws + OFF_CNT);
  int*   offs = (int*)(ws + OFF_OFFS);
  int*   list = (int*)(ws + OFF_LIST);
  int*   tidx = (int*)(ws + OFF_TIDX);
  int*   tpos = (int*)(ws + OFF_TPOS);
  float* tw   = (float*)(ws + OFF_TW);
  unsigned short* gu = (unsigned short*)(ws + OFF_GU);
  unsigned short* y  = (unsigned short*)(ws + OFF_Y);

  hipMemsetAsync(cnt, 0, 128, stream);
  router_kernel<<<T_TOK, 256, 0, stream>>>(x, gw, logits_out, cnt, list, tidx, tpos, tw);
  scan_kernel<<<1, 64, 0, stream>>>(cnt, offs);
  gemm_gu<<<dim3(12, E_NUM), 256, 0, stream>>>(x, gpw, upw, cnt, offs, list, gu);
  silu_mul<<<(T_TOK * TOPK * I_DIM / 8) / 256, 256, 0, stream>>>(gu);
  gemm_down<<<dim3(16, E_NUM), 256, 0, stream>>>(gu, dpw, cnt, offs, y);
  combine_kernel<<<T_TOK, 256, 0, stream>>>(y, tidx, tpos, tw, offs, out);
}

// Round 2
// 794.669 us; speedup vs baseline: 1.0770x; 1.0770x over previous
//
#include <hip/hip_runtime.h>

typedef __attribute__((ext_vector_type(8))) short short8;
typedef __attribute__((ext_vector_type(8))) unsigned short ushort8;
typedef __attribute__((ext_vector_type(4))) float floatx4;

#define T_TOK 1024
#define H_DIM 2048
#define I_DIM 768
#define E_NUM 32
#define TOPK  8

// ---- workspace layout (bytes) ----
#define OFF_CNT   0                      // 32 * 4
#define OFF_OFFS  512                    // 33 * 4
#define OFF_LIST  1024                   // 32*1024*4
#define OFF_TIDX  132096                 // 1024*8*4
#define OFF_TPOS  164864                 // 1024*8*4
#define OFF_TW    197632                 // 1024*8*4
#define OFF_ACT   262144                 // 8192*768*2  = 12,582,912 (bf16)
#define OFF_XG    12845056               // 8192*2048*2 = 33,554,432 (bf16)
#define OFF_Y     OFF_XG                 // y aliases Xg (Xg dead after gemm_gu)

__device__ __forceinline__ unsigned short f2bf(float f) {
  unsigned int u = __builtin_bit_cast(unsigned int, f);
  u += 0x7fffu + ((u >> 16) & 1u);           // RNE
  return (unsigned short)(u >> 16);
}
__device__ __forceinline__ float bf2f(unsigned short h) {
  unsigned int u = ((unsigned int)h) << 16;
  return __builtin_bit_cast(float, u);
}
__device__ __forceinline__ void async_copy16(const void* g, void* l) {
  __builtin_amdgcn_global_load_lds(
      (const __attribute__((address_space(1))) unsigned int*)g,
      (__attribute__((address_space(3))) unsigned int*)l, 16, 0, 0);
}

// ---------------- router: logits (fp32, exact) + softmax + top8 + assignment ----------------
__global__ __launch_bounds__(256) void router_kernel(
    const float* __restrict__ x, const float* __restrict__ gw,
    float* __restrict__ logits_out, int* __restrict__ cnt, int* __restrict__ list,
    int* __restrict__ tidx, int* __restrict__ tpos, float* __restrict__ tw)
{
  int t = blockIdx.x;
  int tid = threadIdx.x;
  int wave = tid >> 6, lane = tid & 63;
  const float* xr = x + (size_t)t * H_DIM;
  float xv[32];
#pragma unroll
  for (int i = 0; i < 32; i++) xv[i] = xr[lane + 64 * i];

  __shared__ float lg[E_NUM];
  for (int ee = 0; ee < 8; ee++) {
    int e = wave * 8 + ee;
    const float* wr = gw + (size_t)e * H_DIM;
    float acc = 0.f;
#pragma unroll
    for (int i = 0; i < 32; i++) acc += xv[i] * wr[lane + 64 * i];
    for (int m = 32; m >= 1; m >>= 1) acc += __shfl_xor(acc, m, 64);
    if (lane == 0) lg[e] = acc;
  }
  __syncthreads();

  if (tid < E_NUM) logits_out[t * E_NUM + tid] = lg[tid];

  if (wave == 0) {
    float logit = (lane < E_NUM) ? lg[lane] : -1e30f;
    float mx = logit;
    for (int m = 16; m >= 1; m >>= 1) mx = fmaxf(mx, __shfl_xor(mx, m, 64));
    float p = (lane < E_NUM) ? expf(logit - mx) : 0.f;
    float sum = p;
    for (int m = 16; m >= 1; m >>= 1) sum += __shfl_xor(sum, m, 64);
    p /= sum;

    float rem = (lane < E_NUM) ? p : -1.f;
    int   seli[TOPK];
    float selw[TOPK];
    float sumw = 0.f;
#pragma unroll
    for (int k = 0; k < TOPK; k++) {
      float v = rem; int i = lane;
      for (int m = 16; m >= 1; m >>= 1) {
        float ov = __shfl_xor(v, m, 64);
        int   oi = __shfl_xor(i, m, 64);
        if (ov > v || (ov == v && oi < i)) { v = ov; i = oi; }
      }
      seli[k] = i; selw[k] = v; sumw += v;
      if (lane == i) rem = -1.f;
    }
    if (lane < TOPK) {
      int e = seli[lane];
      float w = selw[lane] / sumw;
      int pos = atomicAdd(&cnt[e], 1);
      list[e * 1024 + pos] = t;
      tidx[t * TOPK + lane] = e;
      tpos[t * TOPK + lane] = pos;
      tw[t * TOPK + lane] = w;
    }
  }
}

// ---------------- exclusive scan of expert counts ----------------
__global__ void scan_kernel(const int* __restrict__ cnt, int* __restrict__ offs) {
  if (threadIdx.x == 0) {
    int s = 0;
    for (int e = 0; e < E_NUM; e++) { offs[e] = s; s += cnt[e]; }
    offs[E_NUM] = s;
  }
}

// ---------------- gather + convert: Xg[slot][k] = bf16(x[token][k]) ----------------
__global__ __launch_bounds__(256) void gather_x(
    const float* __restrict__ x, const int* __restrict__ tidx,
    const int* __restrict__ tpos, const int* __restrict__ offs,
    unsigned short* __restrict__ xg)
{
  int t = blockIdx.x;
  int tid = threadIdx.x;
  const float* xr = x + (size_t)t * H_DIM + tid * 8;
  floatx4 a = *(const floatx4*)xr;
  floatx4 b = *(const floatx4*)(xr + 4);
  ushort8 p;
#pragma unroll
  for (int j = 0; j < 4; j++) { p[j] = f2bf(a[j]); p[j + 4] = f2bf(b[j]); }
#pragma unroll
  for (int k = 0; k < TOPK; k++) {
    int e = tidx[t * TOPK + k];
    int slot = offs[e] + tpos[t * TOPK + k];
    *(ushort8*)(xg + (size_t)slot * H_DIM + tid * 8) = p;
  }
}

// ---------------- gemm_gu: act = silu(Xg*Wg^T) * (Xg*Wu^T), fused ----------------
// tile M=512 (whole expert), N = 32 gate + 32 up cols. 4 waves, wave w owns rows
// [w*128, w*128+128) x all 64 cols -> 8 m-frags x 4 n-frags (j0,1=gate j2,3=up).
__global__ __launch_bounds__(256, 2) void gemm_gu(
    const unsigned short* __restrict__ xg,
    const float* __restrict__ gpw, const float* __restrict__ upw,
    const int* __restrict__ cnt, const int* __restrict__ offs,
    unsigned short* __restrict__ act)
{
  int bid = blockIdx.x;
  int e = bid & 31;                 // expert -> XCD pinning heuristic
  int nt = bid >> 5;                // 0..23
  int c = cnt[e];
  if (c == 0) return;
  int base = offs[e];
  int n0 = nt * 32;

  __shared__ unsigned char  As[512 * 64];   // 32 KB, bf16 rows of 32, 64B/row
  __shared__ unsigned short Ws[64 * 40];    // 5 KB, padded stride 40

  int tid = threadIdx.x;
  int w = tid >> 6, lane = tid & 63;
  int q = lane >> 4, l15 = lane & 15;

  // W staging: row wr (0..31 gate, 32..63 up), 8-col segment wc
  int wr = tid >> 2, wc = tid & 3;
  const float* wp = (wr < 32 ? gpw + ((size_t)e * I_DIM + n0 + wr) * H_DIM
                             : upw + ((size_t)e * I_DIM + n0 + (wr - 32)) * H_DIM) + wc * 8;
  unsigned short* wdst = &Ws[wr * 40 + wc * 8];

  // A staging: per wave 8 async insts, 16 rows each; XOR col swizzle for banks
  const unsigned short* agp[8];
  unsigned char* aldst[8];
  {
    int rl = lane >> 2;
    int ch = (lane & 3) ^ ((lane >> 3) & 3);
#pragma unroll
    for (int g = 0; g < 8; g++) {
      int rm = w * 128 + g * 16 + rl;
      int slot = base + rm; if (slot > 8191) slot = 8191;
      agp[g] = xg + (size_t)slot * H_DIM + ch * 8;
      aldst[g] = &As[(w * 128 + g * 16) * 64];
    }
  }
  // A frag read addrs (fixed; LDS rewritten in place each k-step)
  const unsigned char* afp[8];
#pragma unroll
  for (int i = 0; i < 8; i++) {
    int row = w * 128 + i * 16 + l15;
    int chunk = q ^ ((row >> 1) & 3);
    afp[i] = &As[row * 64 + chunk * 16];
  }
  const unsigned short* bfp[4];
#pragma unroll
  for (int j = 0; j < 4; j++) bfp[j] = &Ws[(j * 16 + l15) * 40 + q * 8];

  int rem = c - w * 128;
  int ni = rem <= 0 ? 0 : (rem >= 128 ? 8 : ((rem + 15) >> 4));   // active m-frags
  bool wact = ni > 0;

  floatx4 acc[8][4];
#pragma unroll
  for (int i = 0; i < 8; i++)
#pragma unroll
    for (int j = 0; j < 4; j++) acc[i][j] = (floatx4){0.f, 0.f, 0.f, 0.f};

  for (int kt = 0; kt < H_DIM / 32; kt++) {
    if (wact) {
#pragma unroll
      for (int g = 0; g < 8; g++) { async_copy16(agp[g], aldst[g]); agp[g] += 32; }
    }
    floatx4 w0 = *(const floatx4*)wp;
    floatx4 w1 = *(const floatx4*)(wp + 4);
    wp += 32;
    ushort8 pw;
#pragma unroll
    for (int z = 0; z < 4; z++) { pw[z] = f2bf(w0[z]); pw[z + 4] = f2bf(w1[z]); }
    *(ushort8*)wdst = pw;
    __syncthreads();

    short8 bf[4];
#pragma unroll
    for (int j = 0; j < 4; j++) bf[j] = *(const short8*)bfp[j];
#pragma unroll
    for (int i = 0; i < 8; i++) {
      if (i < ni) {
        short8 af = *(const short8*)afp[i];
#pragma unroll
        for (int j = 0; j < 4; j++)
          acc[i][j] = __builtin_amdgcn_mfma_f32_16x16x32_bf16(af, bf[j], acc[i][j], 0, 0, 0);
      }
    }
    __syncthreads();
  }

  // fused SiLU epilogue: act[slot][n0 + j*16 + l15] = silu(g)*u
#pragma unroll
  for (int i = 0; i < 8; i++) {
    if (i < ni) {
#pragma unroll
      for (int r = 0; r < 4; r++) {
        int s = w * 128 + i * 16 + q * 4 + r;
        if (s < c) {
          size_t rowb = (size_t)(base + s) * I_DIM + n0;
#pragma unroll
          for (int j = 0; j < 2; j++) {
            float g = acc[i][j][r];
            float u = acc[i][j + 2][r];
            float sv = g / (1.f + __expf(-g));
            act[rowb + j * 16 + l15] = f2bf(sv * u);
          }
        }
      }
    }
  }
}

// ---------------- gemm_down: y = act * Wd^T ----------------
__global__ __launch_bounds__(256, 2) void gemm_down(
    const unsigned short* __restrict__ act,
    const float* __restrict__ dpw,
    const int* __restrict__ cnt, const int* __restrict__ offs,
    unsigned short* __restrict__ y)
{
  int bid = blockIdx.x;
  int e = bid & 31;
  int nt = bid >> 5;                // 0..31
  int c = cnt[e];
  if (c == 0) return;
  int base = offs[e];
  int h0 = nt * 64;

  __shared__ unsigned char  As[512 * 64];
  __shared__ unsigned short Ws[64 * 40];

  int tid = threadIdx.x;
  int w = tid >> 6, lane = tid & 63;
  int q = lane >> 4, l15 = lane & 15;

  int wr = tid >> 2, wc = tid & 3;
  const float* wp = dpw + ((size_t)e * H_DIM + h0 + wr) * I_DIM + wc * 8;
  unsigned short* wdst = &Ws[wr * 40 + wc * 8];

  const unsigned short* agp[8];
  unsigned char* aldst[8];
  {
    int rl = lane >> 2;
    int ch = (lane & 3) ^ ((lane >> 3) & 3);
#pragma unroll
    for (int g = 0; g < 8; g++) {
      int rm = w * 128 + g * 16 + rl;
      int slot = base + rm; if (slot > 8191) slot = 8191;
      agp[g] = act + (size_t)slot * I_DIM + ch * 8;
      aldst[g] = &As[(w * 128 + g * 16) * 64];
    }
  }
  const unsigned char* afp[8];
#pragma unroll
  for (int i = 0; i < 8; i++) {
    int row = w * 128 + i * 16 + l15;
    int chunk = q ^ ((row >> 1) & 3);
    afp[i] = &As[row * 64 + chunk * 16];
  }
  const unsigned short* bfp[4];
#pragma unroll
  for (int j = 0; j < 4; j++) bfp[j] = &Ws[(j * 16 + l15) * 40 + q * 8];

  int rem = c - w * 128;
  int ni = rem <= 0 ? 0 : (rem >= 128 ? 8 : ((rem + 15) >> 4));
  bool wact = ni > 0;

  floatx4 acc[8][4];
#pragma unroll
  for (int i = 0; i < 8; i++)
#pragma unroll
    for (int j = 0; j < 4; j++) acc[i][j] = (floatx4){0.f, 0.f, 0.f, 0.f};

  for (int kt = 0; kt < I_DIM / 32; kt++) {
    if (wact) {
#pragma unroll
      for (int g = 0; g < 8; g++) { async_copy16(agp[g], aldst[g]); agp[g] += 32; }
    }
    floatx4 w0 = *(const floatx4*)wp;
    floatx4 w1 = *(const floatx4*)(wp + 4);
    wp += 32;
    ushort8 pw;
#pragma unroll
    for (int z = 0; z < 4; z++) { pw[z] = f2bf(w0[z]); pw[z + 4] = f2bf(w1[z]); }
    *(ushort8*)wdst = pw;
    __syncthreads();

    short8 bf[4];
#pragma unroll
    for (int j = 0; j < 4; j++) bf[j] = *(const short8*)bfp[j];
#pragma unroll
    for (int i = 0; i < 8; i++) {
      if (i < ni) {
        short8 af = *(const short8*)afp[i];
#pragma unroll
        for (int j = 0; j < 4; j++)
          acc[i][j] = __builtin_amdgcn_mfma_f32_16x16x32_bf16(af, bf[j], acc[i][j], 0, 0, 0);
      }
    }
    __syncthreads();
  }

#pragma unroll
  for (int i = 0; i < 8; i++) {
    if (i < ni) {
#pragma unroll
      for (int r = 0; r < 4; r++) {
        int s = w * 128 + i * 16 + q * 4 + r;
        if (s < c) {
          size_t rowb = (size_t)(base + s) * H_DIM + h0;
#pragma unroll
          for (int j = 0; j < 4; j++)
            y[rowb + j * 16 + l15] = f2bf(acc[i][j][r]);
        }
      }
    }
  }
}

// ---------------- combine: out[t,h] = sum_k w * y[slot_k, h] ----------------
__global__ __launch_bounds__(256) void combine_kernel(
    const unsigned short* __restrict__ y,
    const int* __restrict__ tidx, const int* __restrict__ tpos,
    const float* __restrict__ tw, const int* __restrict__ offs,
    float* __restrict__ out)
{
  int t = blockIdx.x;
  int tid = threadIdx.x;
  int h = tid * 8;
  float acc[8];
#pragma unroll
  for (int j = 0; j < 8; j++) acc[j] = 0.f;
#pragma unroll
  for (int k = 0; k < TOPK; k++) {
    int e = tidx[t * TOPK + k];
    int p = tpos[t * TOPK + k];
    float w = tw[t * TOPK + k];
    size_t sg = (size_t)offs[e] + p;
    ushort8 v = *(const ushort8*)(y + sg * H_DIM + h);
#pragma unroll
    for (int j = 0; j < 8; j++) acc[j] += w * bf2f(v[j]);
  }
  floatx4 o0 = {acc[0], acc[1], acc[2], acc[3]};
  floatx4 o1 = {acc[4], acc[5], acc[6], acc[7]};
  *(floatx4*)(out + (size_t)t * H_DIM + h) = o0;
  *(floatx4*)(out + (size_t)t * H_DIM + h + 4) = o1;
}

extern "C" void kernel_launch(void* const* d_in, const int* in_sizes, int n_in,
                              void* d_out, int out_size, void* d_ws, size_t ws_size,
                              hipStream_t stream) {
  const float* x   = (const float*)d_in[0];
  const float* gw  = (const float*)d_in[1];
  const float* gpw = (const float*)d_in[2];
  const float* upw = (const float*)d_in[3];
  const float* dpw = (const float*)d_in[4];
  float* out = (float*)d_out;
  float* logits_out = out + (size_t)T_TOK * H_DIM;

  char* ws = (char*)d_ws;
  int*   cnt  = (int*)(ws + OFF_CNT);
  int*   offs = (int*)(ws + OFF_OFFS);
  int*   list = (int*)(ws + OFF_LIST);
  int*   tidx = (int*)(ws + OFF_TIDX);
  int*   tpos = (int*)(ws + OFF_TPOS);
  float* tw   = (float*)(ws + OFF_TW);
  unsigned short* act = (unsigned short*)(ws + OFF_ACT);
  unsigned short* xg  = (unsigned short*)(ws + OFF_XG);
  unsigned short* y   = (unsigned short*)(ws + OFF_Y);   // aliases xg

  hipMemsetAsync(cnt, 0, 128, stream);
  router_kernel<<<T_TOK, 256, 0, stream>>>(x, gw, logits_out, cnt, list, tidx, tpos, tw);
  scan_kernel<<<1, 64, 0, stream>>>(cnt, offs);
  gather_x<<<T_TOK, 256, 0, stream>>>(x, tidx, tpos, offs, xg);
  gemm_gu<<<24 * E_NUM, 256, 0, stream>>>(xg, gpw, upw, cnt, offs, act);
  gemm_down<<<32 * E_NUM, 256, 0, stream>>>(act, dpw, cnt, offs, y);
  combine_kernel<<<T_TOK, 256, 0, stream>>>(y, tidx, tpos, tw, offs, out);
}